// Round 6
// baseline (282.371 us; speedup 1.0000x reference)
//
#include <hip/hip_runtime.h>
#include <hip/hip_bf16.h>
#include <math.h>

// Problem constants (from reference)
#define B_ROWS 4096
#define C_ROWS 2048
#define D_DIM  2048
#define NUM 2
#define MAX_ITER 15
#define NEAREST 3
#define MARGIN 1.0f

typedef __bf16 bf16_t;
typedef bf16_t bf16x8 __attribute__((ext_vector_type(8)));
typedef float f32x4 __attribute__((ext_vector_type(4)));

// ---------------------------------------------------------------------------
// conv: one wave per row, f32 -> bf16 (16B stores) + row sumsq via shuffle.
// Rows [0,4096) = feature, [4096,6144) = centers. 4 waves/block.
// Block 0 also zero-inits the tail_fused sync counters (visible at next
// kernel boundary).
// ---------------------------------------------------------------------------
__global__ __launch_bounds__(256) void conv_rows(const float* __restrict__ F,
                                                 const float* __restrict__ Cn,
                                                 bf16_t* __restrict__ Fb,
                                                 bf16_t* __restrict__ Cb,
                                                 float* __restrict__ f2,
                                                 float* __restrict__ c2,
                                                 int* __restrict__ sync) {
    if (blockIdx.x == 0 && threadIdx.x == 0) { sync[0] = 0; sync[1] = 0; }
    int wave = threadIdx.x >> 6;
    int lane = threadIdx.x & 63;
    int row = blockIdx.x * 4 + wave;          // 0..6143
    const float* p; bf16_t* q; float* sq; int r;
    if (row < B_ROWS) {
        r = row; p = F + (size_t)r * D_DIM; q = Fb + (size_t)r * D_DIM; sq = f2;
    } else {
        r = row - B_ROWS; p = Cn + (size_t)r * D_DIM; q = Cb + (size_t)r * D_DIM; sq = c2;
    }
    float s = 0.0f;
    #pragma unroll
    for (int it = 0; it < 4; ++it) {
        int k = (it * 64 + lane) * 8;         // 8 consecutive floats per lane
        float4 v0 = *(const float4*)(p + k);
        float4 v1 = *(const float4*)(p + k + 4);
        s += v0.x * v0.x + v0.y * v0.y + v0.z * v0.z + v0.w * v0.w;
        s += v1.x * v1.x + v1.y * v1.y + v1.z * v1.z + v1.w * v1.w;
        bf16x8 b;
        b[0] = (bf16_t)v0.x; b[1] = (bf16_t)v0.y; b[2] = (bf16_t)v0.z; b[3] = (bf16_t)v0.w;
        b[4] = (bf16_t)v1.x; b[5] = (bf16_t)v1.y; b[6] = (bf16_t)v1.z; b[7] = (bf16_t)v1.w;
        *(bf16x8*)(q + k) = b;
    }
    #pragma unroll
    for (int off = 32; off >= 1; off >>= 1) s += __shfl_down(s, off);
    if (lane == 0) sq[r] = s;
}

// ---------------------------------------------------------------------------
// Fused bf16 MFMA distance GEMM (Dfc and Dcc in one dispatch), BK=32
// (reverted from BK=64: 128B LDS row stride tripled bank conflicts, +11us):
//   Out[m][n] = a2[m] + c2[n] - 2 * sum_k A[m][k]*Cb[n][k]
// 128x128 tile, 4 waves (2x2 of 64x64), 16x16x32 MFMA.
// ---------------------------------------------------------------------------
__global__ __launch_bounds__(256) void gemm_d2_fused(const bf16_t* __restrict__ Fb,
                                                     const bf16_t* __restrict__ Cb,
                                                     const float* __restrict__ f2,
                                                     const float* __restrict__ c2,
                                                     float* __restrict__ Dfc,
                                                     float* __restrict__ Dcc) {
    __shared__ __align__(16) bf16_t As[128 * 32];
    __shared__ __align__(16) bf16_t Bs[128 * 32];

    const int tid  = threadIdx.x;
    const int wave = tid >> 6;
    const int lane = tid & 63;

    const int by = blockIdx.y;
    const bf16_t* A; const float* a2v; float* Out; int bm;
    if (by < B_ROWS / 128) { A = Fb; a2v = f2; Out = Dfc; bm = by * 128; }
    else { A = Cb; a2v = c2; Out = Dcc; bm = (by - B_ROWS / 128) * 128; }
    const int bn = blockIdx.x * 128;
    const int N = C_ROWS, K = D_DIM;

    const int wm = (wave >> 1) * 64;
    const int wn = (wave & 1) * 64;

    f32x4 acc[4][4] = {};

    const int c0   = wave * 2;
    const int rsub = lane >> 2;           // 0..15
    const int ksub = (lane & 3) * 8;      // 0,8,16,24 (16B)
    const int mrow = lane & 15;
    const int kq   = (lane >> 4) * 8;

    for (int k0 = 0; k0 < K; k0 += 32) {
        #pragma unroll
        for (int is = 0; is < 2; ++is) {
            int chunk = c0 + is;
            int row = chunk * 16 + rsub;
            const bf16_t* gA = A + (size_t)(bm + row) * K + (k0 + ksub);
            const bf16_t* gB = Cb + (size_t)(bn + row) * K + (k0 + ksub);
            __builtin_amdgcn_global_load_lds(
                (const __attribute__((address_space(1))) void*)gA,
                (__attribute__((address_space(3))) void*)&As[chunk * 512], 16, 0, 0);
            __builtin_amdgcn_global_load_lds(
                (const __attribute__((address_space(1))) void*)gB,
                (__attribute__((address_space(3))) void*)&Bs[chunk * 512], 16, 0, 0);
        }
        __syncthreads();

        bf16x8 af[4], bf_[4];
        #pragma unroll
        for (int i = 0; i < 4; ++i) {
            af[i]  = *(const bf16x8*)&As[(wm + i * 16 + mrow) * 32 + kq];
            bf_[i] = *(const bf16x8*)&Bs[(wn + i * 16 + mrow) * 32 + kq];
        }
        #pragma unroll
        for (int i = 0; i < 4; ++i)
            #pragma unroll
            for (int j = 0; j < 4; ++j)
                acc[i][j] = __builtin_amdgcn_mfma_f32_16x16x32_bf16(af[i], bf_[j], acc[i][j], 0, 0, 0);
        __syncthreads();
    }

    // Epilogue: d2 = a2[m] + c2[n] - 2*dot. C/D: col=lane&15, row=(lane>>4)*4+reg
    const int ncol = lane & 15;
    const int r4   = (lane >> 4) * 4;
    #pragma unroll
    for (int i = 0; i < 4; ++i) {
        #pragma unroll
        for (int r = 0; r < 4; ++r) {
            int m = bm + wm + i * 16 + r4 + r;
            float am = a2v[m];
            #pragma unroll
            for (int j = 0; j < 4; ++j) {
                int n = bn + wn + j * 16 + ncol;
                Out[(size_t)m * N + n] = am + c2[n] - 2.0f * acc[i][j][r];
            }
        }
    }
}

// ---------------------------------------------------------------------------
// tail_fused: near3 + select + finalize in ONE dispatch.
//  - blocks [0,512): near3 for rows bid*4+wave (one Dcc row per wave),
//    then release-increment sync[0].
//  - all blocks: acquire-spin until sync[0]==512, then select (one Dfc row
//    per wave, rows bid*4+wave), block partial -> hpart[bid].
//  - last block (ticket on sync[1]) sums hpart and writes the mean.
// Co-residency: small VGPR/LDS => >=5 blocks/CU * 256 CUs >= 1024 blocks,
// so producers always run; spin cannot deadlock.
// ---------------------------------------------------------------------------
__global__ __launch_bounds__(256) void tail_fused(const float* __restrict__ Dcc,
                                                  const float* __restrict__ Dfc,
                                                  int* __restrict__ near3,
                                                  float* __restrict__ hpart,
                                                  int* __restrict__ sync,
                                                  float* __restrict__ out) {
    const int bid  = blockIdx.x;
    const int wave = threadIdx.x >> 6;
    const int lane = threadIdx.x & 63;
    const int gw   = bid * 4 + wave;

    // ---------------- phase A: near3 producers ----------------
    if (bid < C_ROWS / 4) {
        int c = gw;                          // 0..2047
        const float* row = Dcc + (size_t)c * C_ROWS;
        float vals[32];
        #pragma unroll
        for (int j = 0; j < 32; ++j) vals[j] = row[lane + j * 64];
        unsigned int excl = 0;
        for (int pick = 0; pick < NEAREST; ++pick) {
            float bestv = INFINITY; int bestidx = 0x7fffffff;
            #pragma unroll
            for (int j = 0; j < 32; ++j) {
                if (excl & (1u << j)) continue;
                float v = vals[j]; int idx = lane + j * 64;
                if (v < bestv || (v == bestv && idx < bestidx)) { bestv = v; bestidx = idx; }
            }
            for (int off = 32; off >= 1; off >>= 1) {
                float ov = __shfl_down(bestv, off); int oi = __shfl_down(bestidx, off);
                if (ov < bestv || (ov == bestv && oi < bestidx)) { bestv = ov; bestidx = oi; }
            }
            int sel = __shfl(bestidx, 0);
            if (lane == 0) near3[c * NEAREST + pick] = sel;
            if ((sel & 63) == lane) excl |= 1u << (sel >> 6);
        }
        __syncthreads();   // all waves' near3 stores issued & drained (vmcnt)
        if (threadIdx.x == 0)
            __hip_atomic_fetch_add(&sync[0], 1, __ATOMIC_RELEASE, __HIP_MEMORY_SCOPE_AGENT);
    }

    // ---------------- handshake: wait for all near3 ----------------
    if (threadIdx.x == 0) {
        while (__hip_atomic_load(&sync[0], __ATOMIC_ACQUIRE, __HIP_MEMORY_SCOPE_AGENT)
               < C_ROWS / 4) {
            __builtin_amdgcn_s_sleep(1);
        }
    }
    __syncthreads();
    __builtin_amdgcn_fence(__ATOMIC_ACQUIRE, "agent");

    // ---------------- phase B: select ----------------
    {
        int b = gw;                          // 0..4095
        int label = b / NUM;
        const float* row = Dfc + (size_t)b * C_ROWS;
        float vals[32];
        #pragma unroll
        for (int j = 0; j < 32; ++j) {
            int cc = lane + j * 64;
            float v = row[cc];
            vals[j] = (cc == label) ? INFINITY : v;
        }
        unsigned int excl = 0;
        float min_diff = 0.0f;
        int found = 0;
        for (int it = 0; it < MAX_ITER; ++it) {
            float bestv = INFINITY; int bestidx = 0x7fffffff;
            #pragma unroll
            for (int j = 0; j < 32; ++j) {
                if (excl & (1u << j)) continue;
                float v = vals[j]; int idx = lane + j * 64;
                if (v < bestv || (v == bestv && idx < bestidx)) { bestv = v; bestidx = idx; }
            }
            for (int off = 32; off >= 1; off >>= 1) {
                float ov = __shfl_down(bestv, off); int oi = __shfl_down(bestidx, off);
                if (ov < bestv || (ov == bestv && oi < bestidx)) { bestv = ov; bestidx = oi; }
            }
            int sel = __shfl(bestidx, 0);
            float selv = __shfl(bestv, 0);
            bool trusted = (near3[sel * NEAREST + 0] != label) &&
                           (near3[sel * NEAREST + 1] != label) &&
                           (near3[sel * NEAREST + 2] != label);
            if (trusted) { min_diff = sqrtf(fmaxf(selv, 0.0f)); found = 1; break; }
            if ((sel & 63) == lane) excl |= 1u << (sel >> 6);
        }
        __shared__ float hs[4];
        if (lane == 0) {
            float same = sqrtf(fmaxf(row[label], 0.0f));
            float md = found ? min_diff : 0.0f;
            hs[wave] = fmaxf(MARGIN + same - md, 0.0f);
        }
        __syncthreads();
        if (threadIdx.x == 0) hpart[bid] = hs[0] + hs[1] + hs[2] + hs[3];
    }

    // ---------------- phase C: last block finalizes ----------------
    __syncthreads();   // hpart store drained
    __shared__ int is_last;
    if (threadIdx.x == 0) {
        int t = __hip_atomic_fetch_add(&sync[1], 1, __ATOMIC_ACQ_REL, __HIP_MEMORY_SCOPE_AGENT);
        is_last = (t == (B_ROWS / 4) - 1);
    }
    __syncthreads();
    if (is_last) {
        __builtin_amdgcn_fence(__ATOMIC_ACQUIRE, "agent");
        float s = 0.0f;
        for (int i = threadIdx.x; i < B_ROWS / 4; i += 256) s += hpart[i];
        #pragma unroll
        for (int off = 32; off >= 1; off >>= 1) s += __shfl_down(s, off);
        __shared__ float red[4];
        if (lane == 0) red[wave] = s;
        __syncthreads();
        if (threadIdx.x == 0)
            out[0] = (red[0] + red[1] + red[2] + red[3]) * (1.0f / (float)B_ROWS);
    }
}

// ---------------------------------------------------------------------------
extern "C" void kernel_launch(void* const* d_in, const int* in_sizes, int n_in,
                              void* d_out, int out_size, void* d_ws, size_t ws_size,
                              hipStream_t stream) {
    const float* feature = (const float*)d_in[0];  // 4096 x 2048
    const float* centers = (const float*)d_in[1];  // 2048 x 2048
    float* out = (float*)d_out;                    // scalar

    // Workspace layout
    float*  Dfc  = (float*)d_ws;                             // 4096*2048 f32
    float*  Dcc  = Dfc + (size_t)B_ROWS * C_ROWS;            // 2048*2048 f32
    bf16_t* Fbf  = (bf16_t*)(Dcc + (size_t)C_ROWS * C_ROWS); // 4096*2048 bf16
    bf16_t* Cbf  = Fbf + (size_t)B_ROWS * D_DIM;             // 2048*2048 bf16
    float*  f2   = (float*)(Cbf + (size_t)C_ROWS * D_DIM);   // 4096
    float*  c2   = f2 + B_ROWS;                              // 2048
    int*    near3 = (int*)(c2 + C_ROWS);                     // 2048*3
    float*  hpart = (float*)(near3 + C_ROWS * NEAREST);      // 1024
    int*    sync  = (int*)(hpart + B_ROWS / 4);              // 2

    conv_rows<<<(B_ROWS + C_ROWS) / 4, 256, 0, stream>>>(feature, centers, Fbf, Cbf,
                                                         f2, c2, sync);

    // Both distance matrices in one dispatch: grid (16, 32+16) = 768 blocks.
    gemm_d2_fused<<<dim3(C_ROWS / 128, B_ROWS / 128 + C_ROWS / 128), 256, 0, stream>>>(
        Fbf, Cbf, f2, c2, Dfc, Dcc);

    // near3 + select + finalize, one dispatch.
    tail_fused<<<B_ROWS / 4, 256, 0, stream>>>(Dcc, Dfc, near3, hpart, sync, out);
}

// Round 8
// 171.340 us; speedup vs baseline: 1.6480x; 1.6480x over previous
//
#include <hip/hip_runtime.h>
#include <hip/hip_bf16.h>
#include <math.h>

// Problem constants (from reference)
#define B_ROWS 4096
#define C_ROWS 2048
#define D_DIM  2048
#define NUM 2
#define MAX_ITER 15
#define NEAREST 3
#define MARGIN 1.0f

typedef __bf16 bf16_t;
typedef bf16_t bf16x8 __attribute__((ext_vector_type(8)));
typedef float f32x4 __attribute__((ext_vector_type(4)));

// ---------------------------------------------------------------------------
// conv: one wave per row, f32 -> bf16 (16B stores) + row sumsq via shuffle.
// Rows [0,4096) = feature, [4096,6144) = centers. 4 waves/block.
// Block 0 zero-inits out (select accumulates onto it; stream order makes it
// visible).
// ---------------------------------------------------------------------------
__global__ __launch_bounds__(256) void conv_rows(const float* __restrict__ F,
                                                 const float* __restrict__ Cn,
                                                 bf16_t* __restrict__ Fb,
                                                 bf16_t* __restrict__ Cb,
                                                 float* __restrict__ f2,
                                                 float* __restrict__ c2,
                                                 float* __restrict__ out) {
    if (blockIdx.x == 0 && threadIdx.x == 0) out[0] = 0.0f;
    int wave = threadIdx.x >> 6;
    int lane = threadIdx.x & 63;
    int row = blockIdx.x * 4 + wave;          // 0..6143
    const float* p; bf16_t* q; float* sq; int r;
    if (row < B_ROWS) {
        r = row; p = F + (size_t)r * D_DIM; q = Fb + (size_t)r * D_DIM; sq = f2;
    } else {
        r = row - B_ROWS; p = Cn + (size_t)r * D_DIM; q = Cb + (size_t)r * D_DIM; sq = c2;
    }
    float s = 0.0f;
    #pragma unroll
    for (int it = 0; it < 4; ++it) {
        int k = (it * 64 + lane) * 8;         // 8 consecutive floats per lane
        float4 v0 = *(const float4*)(p + k);
        float4 v1 = *(const float4*)(p + k + 4);
        s += v0.x * v0.x + v0.y * v0.y + v0.z * v0.z + v0.w * v0.w;
        s += v1.x * v1.x + v1.y * v1.y + v1.z * v1.z + v1.w * v1.w;
        bf16x8 b;
        b[0] = (bf16_t)v0.x; b[1] = (bf16_t)v0.y; b[2] = (bf16_t)v0.z; b[3] = (bf16_t)v0.w;
        b[4] = (bf16_t)v1.x; b[5] = (bf16_t)v1.y; b[6] = (bf16_t)v1.z; b[7] = (bf16_t)v1.w;
        *(bf16x8*)(q + k) = b;
    }
    #pragma unroll
    for (int off = 32; off >= 1; off >>= 1) s += __shfl_down(s, off);
    if (lane == 0) sq[r] = s;
}

// ---------------------------------------------------------------------------
// Fused bf16 MFMA distance GEMM (Dfc and Dcc in one dispatch).
// BK=64 as TWO split [128][32] K-panels (64B LDS row stride = same banking as
// the measured-fast BK=32; half the vmcnt(0)+barrier drains per K-element).
// PITFALL (R7): global_load_lds imm offset != 0 corrupts the transfer — the
// offset participates in the LDS-side address. ALWAYS pass offset=0 and bake
// the displacement into the pointer (gA + 32 below).
// 128x128 tile, 4 waves (2x2 of 64x64), 16x16x32 MFMA.
//   Out[m][n] = a2[m] + c2[n] - 2 * sum_k A[m][k]*Cb[n][k]
// ---------------------------------------------------------------------------
__global__ __launch_bounds__(256, 3) void gemm_d2_fused(const bf16_t* __restrict__ Fb,
                                                        const bf16_t* __restrict__ Cb,
                                                        const float* __restrict__ f2,
                                                        const float* __restrict__ c2,
                                                        float* __restrict__ Dfc,
                                                        float* __restrict__ Dcc) {
    __shared__ __align__(16) bf16_t As[2][128 * 32];
    __shared__ __align__(16) bf16_t Bs[2][128 * 32];

    const int tid  = threadIdx.x;
    const int wave = tid >> 6;
    const int lane = tid & 63;

    const int by = blockIdx.y;
    const bf16_t* A; const float* a2v; float* Out; int bm;
    if (by < B_ROWS / 128) { A = Fb; a2v = f2; Out = Dfc; bm = by * 128; }
    else { A = Cb; a2v = c2; Out = Dcc; bm = (by - B_ROWS / 128) * 128; }
    const int bn = blockIdx.x * 128;
    const int N = C_ROWS, K = D_DIM;

    const int wm = (wave >> 1) * 64;
    const int wn = (wave & 1) * 64;

    f32x4 acc[4][4] = {};

    const int c0   = wave * 2;
    const int rsub = lane >> 2;           // 0..15
    const int ksub = (lane & 3) * 8;      // 0,8,16,24 (16B)
    const int mrow = lane & 15;
    const int kq   = (lane >> 4) * 8;

    for (int k0 = 0; k0 < K; k0 += 64) {
        #pragma unroll
        for (int is = 0; is < 2; ++is) {
            int chunk = c0 + is;
            int row = chunk * 16 + rsub;
            const bf16_t* gA0 = A  + (size_t)(bm + row) * K + (k0 + ksub);
            const bf16_t* gB0 = Cb + (size_t)(bn + row) * K + (k0 + ksub);
            const bf16_t* gA1 = gA0 + 32;   // k0 + [32,64): explicit pointer,
            const bf16_t* gB1 = gB0 + 32;   // NEVER the builtin imm offset
            __builtin_amdgcn_global_load_lds(
                (const __attribute__((address_space(1))) void*)gA0,
                (__attribute__((address_space(3))) void*)&As[0][chunk * 512], 16, 0, 0);
            __builtin_amdgcn_global_load_lds(
                (const __attribute__((address_space(1))) void*)gB0,
                (__attribute__((address_space(3))) void*)&Bs[0][chunk * 512], 16, 0, 0);
            __builtin_amdgcn_global_load_lds(
                (const __attribute__((address_space(1))) void*)gA1,
                (__attribute__((address_space(3))) void*)&As[1][chunk * 512], 16, 0, 0);
            __builtin_amdgcn_global_load_lds(
                (const __attribute__((address_space(1))) void*)gB1,
                (__attribute__((address_space(3))) void*)&Bs[1][chunk * 512], 16, 0, 0);
        }
        __syncthreads();

        #pragma unroll
        for (int h = 0; h < 2; ++h) {
            bf16x8 af[4], bf_[4];
            #pragma unroll
            for (int i = 0; i < 4; ++i) {
                af[i]  = *(const bf16x8*)&As[h][(wm + i * 16 + mrow) * 32 + kq];
                bf_[i] = *(const bf16x8*)&Bs[h][(wn + i * 16 + mrow) * 32 + kq];
            }
            #pragma unroll
            for (int i = 0; i < 4; ++i)
                #pragma unroll
                for (int j = 0; j < 4; ++j)
                    acc[i][j] = __builtin_amdgcn_mfma_f32_16x16x32_bf16(af[i], bf_[j], acc[i][j], 0, 0, 0);
        }
        __syncthreads();
    }

    // Epilogue: d2 = a2[m] + c2[n] - 2*dot. C/D: col=lane&15, row=(lane>>4)*4+reg
    const int ncol = lane & 15;
    const int r4   = (lane >> 4) * 4;
    #pragma unroll
    for (int i = 0; i < 4; ++i) {
        #pragma unroll
        for (int r = 0; r < 4; ++r) {
            int m = bm + wm + i * 16 + r4 + r;
            float am = a2v[m];
            #pragma unroll
            for (int j = 0; j < 4; ++j) {
                int n = bn + wn + j * 16 + ncol;
                Out[(size_t)m * N + n] = am + c2[n] - 2.0f * acc[i][j][r];
            }
        }
    }
}

// ---------------------------------------------------------------------------
// near3: indices of 3 smallest per Dcc row. 4 waves/block, one row per wave.
// ---------------------------------------------------------------------------
__global__ __launch_bounds__(256) void near3_kernel(const float* __restrict__ Dcc,
                                                    int* __restrict__ near3, int C) {
    int wave = threadIdx.x >> 6, lane = threadIdx.x & 63;
    int c = blockIdx.x * 4 + wave;
    const float* row = Dcc + (size_t)c * C;
    float vals[32];
    #pragma unroll
    for (int j = 0; j < 32; ++j) vals[j] = row[lane + j * 64];
    unsigned int excl = 0;
    for (int pick = 0; pick < NEAREST; ++pick) {
        float bestv = INFINITY; int bestidx = 0x7fffffff;
        #pragma unroll
        for (int j = 0; j < 32; ++j) {
            if (excl & (1u << j)) continue;
            float v = vals[j]; int idx = lane + j * 64;
            if (v < bestv || (v == bestv && idx < bestidx)) { bestv = v; bestidx = idx; }
        }
        for (int off = 32; off >= 1; off >>= 1) {
            float ov = __shfl_down(bestv, off); int oi = __shfl_down(bestidx, off);
            if (ov < bestv || (ov == bestv && oi < bestidx)) { bestv = ov; bestidx = oi; }
        }
        int sel = __shfl(bestidx, 0);
        if (lane == 0) near3[c * NEAREST + pick] = sel;
        if ((sel & 63) == lane) excl |= 1u << (sel >> 6);
    }
}

// ---------------------------------------------------------------------------
// select: per feature row, iterative argmin w/ exclusion, first trusted.
// 4 waves/block; one atomicAdd per block onto out (zero-inited by conv).
// ---------------------------------------------------------------------------
__global__ __launch_bounds__(256) void select_kernel(const float* __restrict__ Dfc,
                                                     const int* __restrict__ near3,
                                                     float* __restrict__ out, int C) {
    int wave = threadIdx.x >> 6, lane = threadIdx.x & 63;
    int b = blockIdx.x * 4 + wave;
    int label = b / NUM;
    const float* row = Dfc + (size_t)b * C;
    float vals[32];
    #pragma unroll
    for (int j = 0; j < 32; ++j) {
        int cc = lane + j * 64;
        float v = row[cc];
        vals[j] = (cc == label) ? INFINITY : v;
    }
    unsigned int excl = 0;
    float min_diff = 0.0f;
    int found = 0;
    for (int it = 0; it < MAX_ITER; ++it) {
        float bestv = INFINITY; int bestidx = 0x7fffffff;
        #pragma unroll
        for (int j = 0; j < 32; ++j) {
            if (excl & (1u << j)) continue;
            float v = vals[j]; int idx = lane + j * 64;
            if (v < bestv || (v == bestv && idx < bestidx)) { bestv = v; bestidx = idx; }
        }
        for (int off = 32; off >= 1; off >>= 1) {
            float ov = __shfl_down(bestv, off); int oi = __shfl_down(bestidx, off);
            if (ov < bestv || (ov == bestv && oi < bestidx)) { bestv = ov; bestidx = oi; }
        }
        int sel = __shfl(bestidx, 0);
        float selv = __shfl(bestv, 0);
        bool trusted = (near3[sel * NEAREST + 0] != label) &&
                       (near3[sel * NEAREST + 1] != label) &&
                       (near3[sel * NEAREST + 2] != label);
        if (trusted) { min_diff = sqrtf(fmaxf(selv, 0.0f)); found = 1; break; }
        if ((sel & 63) == lane) excl |= 1u << (sel >> 6);
    }
    __shared__ float hs[4];
    if (lane == 0) {
        float same = sqrtf(fmaxf(row[label], 0.0f));
        float md = found ? min_diff : 0.0f;
        hs[wave] = fmaxf(MARGIN + same - md, 0.0f);
    }
    __syncthreads();
    if (threadIdx.x == 0)
        atomicAdd(out, (hs[0] + hs[1] + hs[2] + hs[3]) * (1.0f / (float)B_ROWS));
}

// ---------------------------------------------------------------------------
extern "C" void kernel_launch(void* const* d_in, const int* in_sizes, int n_in,
                              void* d_out, int out_size, void* d_ws, size_t ws_size,
                              hipStream_t stream) {
    const float* feature = (const float*)d_in[0];  // 4096 x 2048
    const float* centers = (const float*)d_in[1];  // 2048 x 2048
    float* out = (float*)d_out;                    // scalar

    // Workspace layout
    float*  Dfc  = (float*)d_ws;                             // 4096*2048 f32
    float*  Dcc  = Dfc + (size_t)B_ROWS * C_ROWS;            // 2048*2048 f32
    bf16_t* Fbf  = (bf16_t*)(Dcc + (size_t)C_ROWS * C_ROWS); // 4096*2048 bf16
    bf16_t* Cbf  = Fbf + (size_t)B_ROWS * D_DIM;             // 2048*2048 bf16
    float*  f2   = (float*)(Cbf + (size_t)C_ROWS * D_DIM);   // 4096
    float*  c2   = f2 + B_ROWS;                              // 2048
    int*    near3 = (int*)(c2 + C_ROWS);                     // 2048*3

    conv_rows<<<(B_ROWS + C_ROWS) / 4, 256, 0, stream>>>(feature, centers, Fbf, Cbf,
                                                         f2, c2, out);

    // Both distance matrices in one dispatch: grid (16, 32+16) = 768 blocks.
    gemm_d2_fused<<<dim3(C_ROWS / 128, B_ROWS / 128 + C_ROWS / 128), 256, 0, stream>>>(
        Fbf, Cbf, f2, c2, Dfc, Dcc);

    near3_kernel<<<C_ROWS / 4, 256, 0, stream>>>(Dcc, near3, C_ROWS);

    select_kernel<<<B_ROWS / 4, 256, 0, stream>>>(Dfc, near3, out, C_ROWS);
}

// Round 9
// 166.720 us; speedup vs baseline: 1.6937x; 1.0277x over previous
//
#include <hip/hip_runtime.h>
#include <hip/hip_bf16.h>
#include <math.h>

// Problem constants (from reference)
#define B_ROWS 4096
#define C_ROWS 2048
#define D_DIM  2048
#define NUM 2
#define MAX_ITER 15
#define NEAREST 3
#define MARGIN 1.0f

typedef __bf16 bf16_t;
typedef bf16_t bf16x8 __attribute__((ext_vector_type(8)));
typedef float f32x4 __attribute__((ext_vector_type(4)));

// ---------------------------------------------------------------------------
// conv: one wave per row, f32 -> bf16 (16B stores) + row sumsq via shuffle.
// Rows [0,4096) = feature, [4096,6144) = centers. 4 waves/block.
// Block 0 zero-inits out (select accumulates onto it; stream order makes it
// visible).
// ---------------------------------------------------------------------------
__global__ __launch_bounds__(256) void conv_rows(const float* __restrict__ F,
                                                 const float* __restrict__ Cn,
                                                 bf16_t* __restrict__ Fb,
                                                 bf16_t* __restrict__ Cb,
                                                 float* __restrict__ f2,
                                                 float* __restrict__ c2,
                                                 float* __restrict__ out) {
    if (blockIdx.x == 0 && threadIdx.x == 0) out[0] = 0.0f;
    int wave = threadIdx.x >> 6;
    int lane = threadIdx.x & 63;
    int row = blockIdx.x * 4 + wave;          // 0..6143
    const float* p; bf16_t* q; float* sq; int r;
    if (row < B_ROWS) {
        r = row; p = F + (size_t)r * D_DIM; q = Fb + (size_t)r * D_DIM; sq = f2;
    } else {
        r = row - B_ROWS; p = Cn + (size_t)r * D_DIM; q = Cb + (size_t)r * D_DIM; sq = c2;
    }
    float s = 0.0f;
    #pragma unroll
    for (int it = 0; it < 4; ++it) {
        int k = (it * 64 + lane) * 8;         // 8 consecutive floats per lane
        float4 v0 = *(const float4*)(p + k);
        float4 v1 = *(const float4*)(p + k + 4);
        s += v0.x * v0.x + v0.y * v0.y + v0.z * v0.z + v0.w * v0.w;
        s += v1.x * v1.x + v1.y * v1.y + v1.z * v1.z + v1.w * v1.w;
        bf16x8 b;
        b[0] = (bf16_t)v0.x; b[1] = (bf16_t)v0.y; b[2] = (bf16_t)v0.z; b[3] = (bf16_t)v0.w;
        b[4] = (bf16_t)v1.x; b[5] = (bf16_t)v1.y; b[6] = (bf16_t)v1.z; b[7] = (bf16_t)v1.w;
        *(bf16x8*)(q + k) = b;
    }
    #pragma unroll
    for (int off = 32; off >= 1; off >>= 1) s += __shfl_down(s, off);
    if (lane == 0) sq[r] = s;
}

// ---------------------------------------------------------------------------
// Fused bf16 MFMA distance GEMM (Dfc and Dcc in one dispatch).
// BK=64 as TWO split [128][32] K-panels (64B LDS row stride = same banking as
// BK=32; half the vmcnt(0)+barrier drains per K-element). Measured R8:
// 63.8us / 807 TF, MfmaUtil 32%.
// PITFALL (R7): global_load_lds imm offset != 0 corrupts the transfer — the
// offset participates in the LDS-side address. ALWAYS pass offset=0 and bake
// the displacement into the pointer (gA + 32 below).
// 128x128 tile, 4 waves (2x2 of 64x64), 16x16x32 MFMA.
//   Out[m][n] = a2[m] + c2[n] - 2 * sum_k A[m][k]*Cb[n][k]
// ---------------------------------------------------------------------------
__global__ __launch_bounds__(256, 3) void gemm_d2_fused(const bf16_t* __restrict__ Fb,
                                                        const bf16_t* __restrict__ Cb,
                                                        const float* __restrict__ f2,
                                                        const float* __restrict__ c2,
                                                        float* __restrict__ Dfc,
                                                        float* __restrict__ Dcc) {
    __shared__ __align__(16) bf16_t As[2][128 * 32];
    __shared__ __align__(16) bf16_t Bs[2][128 * 32];

    const int tid  = threadIdx.x;
    const int wave = tid >> 6;
    const int lane = tid & 63;

    const int by = blockIdx.y;
    const bf16_t* A; const float* a2v; float* Out; int bm;
    if (by < B_ROWS / 128) { A = Fb; a2v = f2; Out = Dfc; bm = by * 128; }
    else { A = Cb; a2v = c2; Out = Dcc; bm = (by - B_ROWS / 128) * 128; }
    const int bn = blockIdx.x * 128;
    const int N = C_ROWS, K = D_DIM;

    const int wm = (wave >> 1) * 64;
    const int wn = (wave & 1) * 64;

    f32x4 acc[4][4] = {};

    const int c0   = wave * 2;
    const int rsub = lane >> 2;           // 0..15
    const int ksub = (lane & 3) * 8;      // 0,8,16,24 (16B)
    const int mrow = lane & 15;
    const int kq   = (lane >> 4) * 8;

    for (int k0 = 0; k0 < K; k0 += 64) {
        #pragma unroll
        for (int is = 0; is < 2; ++is) {
            int chunk = c0 + is;
            int row = chunk * 16 + rsub;
            const bf16_t* gA0 = A  + (size_t)(bm + row) * K + (k0 + ksub);
            const bf16_t* gB0 = Cb + (size_t)(bn + row) * K + (k0 + ksub);
            const bf16_t* gA1 = gA0 + 32;   // k0 + [32,64): explicit pointer,
            const bf16_t* gB1 = gB0 + 32;   // NEVER the builtin imm offset
            __builtin_amdgcn_global_load_lds(
                (const __attribute__((address_space(1))) void*)gA0,
                (__attribute__((address_space(3))) void*)&As[0][chunk * 512], 16, 0, 0);
            __builtin_amdgcn_global_load_lds(
                (const __attribute__((address_space(1))) void*)gB0,
                (__attribute__((address_space(3))) void*)&Bs[0][chunk * 512], 16, 0, 0);
            __builtin_amdgcn_global_load_lds(
                (const __attribute__((address_space(1))) void*)gA1,
                (__attribute__((address_space(3))) void*)&As[1][chunk * 512], 16, 0, 0);
            __builtin_amdgcn_global_load_lds(
                (const __attribute__((address_space(1))) void*)gB1,
                (__attribute__((address_space(3))) void*)&Bs[1][chunk * 512], 16, 0, 0);
        }
        __syncthreads();

        #pragma unroll
        for (int h = 0; h < 2; ++h) {
            bf16x8 af[4], bf_[4];
            #pragma unroll
            for (int i = 0; i < 4; ++i) {
                af[i]  = *(const bf16x8*)&As[h][(wm + i * 16 + mrow) * 32 + kq];
                bf_[i] = *(const bf16x8*)&Bs[h][(wn + i * 16 + mrow) * 32 + kq];
            }
            #pragma unroll
            for (int i = 0; i < 4; ++i)
                #pragma unroll
                for (int j = 0; j < 4; ++j)
                    acc[i][j] = __builtin_amdgcn_mfma_f32_16x16x32_bf16(af[i], bf_[j], acc[i][j], 0, 0, 0);
        }
        __syncthreads();
    }

    // Epilogue: d2 = a2[m] + c2[n] - 2*dot. C/D: col=lane&15, row=(lane>>4)*4+reg
    const int ncol = lane & 15;
    const int r4   = (lane >> 4) * 4;
    #pragma unroll
    for (int i = 0; i < 4; ++i) {
        #pragma unroll
        for (int r = 0; r < 4; ++r) {
            int m = bm + wm + i * 16 + r4 + r;
            float am = a2v[m];
            #pragma unroll
            for (int j = 0; j < 4; ++j) {
                int n = bn + wn + j * 16 + ncol;
                Out[(size_t)m * N + n] = am + c2[n] - 2.0f * acc[i][j][r];
            }
        }
    }
}

// ---------------------------------------------------------------------------
// select v2: per feature row, iterative argmin w/ exclusion; trust test is
// computed ON DEMAND from Dcc (no near3 array, no near3 dispatch):
//   label in near3[sel]  <=>  #{ j : (Dcc[sel][j], j) <lex (Dcc[sel][label],
//   label) } < NEAREST     (jnp.argsort is stable -> lexicographic order)
// 4 waves/block, one row per wave; one atomicAdd per block onto out.
// ---------------------------------------------------------------------------
__global__ __launch_bounds__(256) void select_kernel(const float* __restrict__ Dfc,
                                                     const float* __restrict__ Dcc,
                                                     float* __restrict__ out, int C) {
    int wave = threadIdx.x >> 6, lane = threadIdx.x & 63;
    int b = blockIdx.x * 4 + wave;
    int label = b / NUM;
    const float* row = Dfc + (size_t)b * C;
    float vals[32];
    #pragma unroll
    for (int j = 0; j < 32; ++j) {
        int cc = lane + j * 64;
        float v = row[cc];
        vals[j] = (cc == label) ? INFINITY : v;
    }
    unsigned int excl = 0;
    float min_diff = 0.0f;
    int found = 0;
    for (int it = 0; it < MAX_ITER; ++it) {
        float bestv = INFINITY; int bestidx = 0x7fffffff;
        #pragma unroll
        for (int j = 0; j < 32; ++j) {
            if (excl & (1u << j)) continue;
            float v = vals[j]; int idx = lane + j * 64;
            if (v < bestv || (v == bestv && idx < bestidx)) { bestv = v; bestidx = idx; }
        }
        for (int off = 32; off >= 1; off >>= 1) {
            float ov = __shfl_down(bestv, off); int oi = __shfl_down(bestidx, off);
            if (ov < bestv || (ov == bestv && oi < bestidx)) { bestv = ov; bestidx = oi; }
        }
        int sel = __shfl(bestidx, 0);
        float selv = __shfl(bestv, 0);

        // --- on-demand trust: count lex-smaller entries of Dcc row sel ---
        const float* crow = Dcc + (size_t)sel * C;
        float dl = crow[label];                 // uniform address: broadcast load
        int cnt = 0;
        #pragma unroll
        for (int j = 0; j < 32; ++j) {
            int idx = lane + j * 64;
            float v = crow[idx];
            cnt += (v < dl || (v == dl && idx < label)) ? 1 : 0;
        }
        #pragma unroll
        for (int off = 32; off >= 1; off >>= 1) cnt += __shfl_down(cnt, off);
        cnt = __shfl(cnt, 0);
        bool trusted = (cnt >= NEAREST);

        if (trusted) { min_diff = sqrtf(fmaxf(selv, 0.0f)); found = 1; break; }
        if ((sel & 63) == lane) excl |= 1u << (sel >> 6);
    }
    __shared__ float hs[4];
    if (lane == 0) {
        float same = sqrtf(fmaxf(row[label], 0.0f));
        float md = found ? min_diff : 0.0f;
        hs[wave] = fmaxf(MARGIN + same - md, 0.0f);
    }
    __syncthreads();
    if (threadIdx.x == 0)
        atomicAdd(out, (hs[0] + hs[1] + hs[2] + hs[3]) * (1.0f / (float)B_ROWS));
}

// ---------------------------------------------------------------------------
extern "C" void kernel_launch(void* const* d_in, const int* in_sizes, int n_in,
                              void* d_out, int out_size, void* d_ws, size_t ws_size,
                              hipStream_t stream) {
    const float* feature = (const float*)d_in[0];  // 4096 x 2048
    const float* centers = (const float*)d_in[1];  // 2048 x 2048
    float* out = (float*)d_out;                    // scalar

    // Workspace layout
    float*  Dfc  = (float*)d_ws;                             // 4096*2048 f32
    float*  Dcc  = Dfc + (size_t)B_ROWS * C_ROWS;            // 2048*2048 f32
    bf16_t* Fbf  = (bf16_t*)(Dcc + (size_t)C_ROWS * C_ROWS); // 4096*2048 bf16
    bf16_t* Cbf  = Fbf + (size_t)B_ROWS * D_DIM;             // 2048*2048 bf16
    float*  f2   = (float*)(Cbf + (size_t)C_ROWS * D_DIM);   // 4096
    float*  c2   = f2 + B_ROWS;                              // 2048

    conv_rows<<<(B_ROWS + C_ROWS) / 4, 256, 0, stream>>>(feature, centers, Fbf, Cbf,
                                                         f2, c2, out);

    // Both distance matrices in one dispatch: grid (16, 32+16) = 768 blocks.
    gemm_d2_fused<<<dim3(C_ROWS / 128, B_ROWS / 128 + C_ROWS / 128), 256, 0, stream>>>(
        Fbf, Cbf, f2, c2, Dfc, Dcc);

    // select with on-demand trust (reads Dcc directly; no near3 dispatch).
    select_kernel<<<B_ROWS / 4, 256, 0, stream>>>(Dfc, Dcc, out, C_ROWS);
}

// Round 10
// 162.273 us; speedup vs baseline: 1.7401x; 1.0274x over previous
//
#include <hip/hip_runtime.h>
#include <hip/hip_bf16.h>
#include <math.h>

// Problem constants (from reference)
#define B_ROWS 4096
#define C_ROWS 2048
#define D_DIM  2048
#define NUM 2
#define MAX_ITER 15
#define NEAREST 3
#define MARGIN 1.0f

typedef __bf16 bf16_t;
typedef bf16_t bf16x8 __attribute__((ext_vector_type(8)));
typedef float f32x4 __attribute__((ext_vector_type(4)));

// ---------------------------------------------------------------------------
// conv: one wave per row, f32 -> bf16 (16B stores) + row sumsq via shuffle.
// Rows [0,4096) = feature, [4096,6144) = centers. 4 waves/block.
// Block 0 zero-inits out (select accumulates onto it; stream order makes it
// visible).
// ---------------------------------------------------------------------------
__global__ __launch_bounds__(256) void conv_rows(const float* __restrict__ F,
                                                 const float* __restrict__ Cn,
                                                 bf16_t* __restrict__ Fb,
                                                 bf16_t* __restrict__ Cb,
                                                 float* __restrict__ f2,
                                                 float* __restrict__ c2,
                                                 float* __restrict__ out) {
    if (blockIdx.x == 0 && threadIdx.x == 0) out[0] = 0.0f;
    int wave = threadIdx.x >> 6;
    int lane = threadIdx.x & 63;
    int row = blockIdx.x * 4 + wave;          // 0..6143
    const float* p; bf16_t* q; float* sq; int r;
    if (row < B_ROWS) {
        r = row; p = F + (size_t)r * D_DIM; q = Fb + (size_t)r * D_DIM; sq = f2;
    } else {
        r = row - B_ROWS; p = Cn + (size_t)r * D_DIM; q = Cb + (size_t)r * D_DIM; sq = c2;
    }
    float s = 0.0f;
    #pragma unroll
    for (int it = 0; it < 4; ++it) {
        int k = (it * 64 + lane) * 8;         // 8 consecutive floats per lane
        float4 v0 = *(const float4*)(p + k);
        float4 v1 = *(const float4*)(p + k + 4);
        s += v0.x * v0.x + v0.y * v0.y + v0.z * v0.z + v0.w * v0.w;
        s += v1.x * v1.x + v1.y * v1.y + v1.z * v1.z + v1.w * v1.w;
        bf16x8 b;
        b[0] = (bf16_t)v0.x; b[1] = (bf16_t)v0.y; b[2] = (bf16_t)v0.z; b[3] = (bf16_t)v0.w;
        b[4] = (bf16_t)v1.x; b[5] = (bf16_t)v1.y; b[6] = (bf16_t)v1.z; b[7] = (bf16_t)v1.w;
        *(bf16x8*)(q + k) = b;
    }
    #pragma unroll
    for (int off = 32; off >= 1; off >>= 1) s += __shfl_down(s, off);
    if (lane == 0) sq[r] = s;
}

// ---------------------------------------------------------------------------
// Fused bf16 MFMA distance GEMM (Dfc and Dcc in one dispatch).
// BK=64 as TWO split [128][32] K-panels (64B LDS row stride = same banking as
// BK=32; half the vmcnt(0)+barrier drains per K-element). Measured R8:
// 63.8us / 807 TF, MfmaUtil 32%.
// PITFALL (R7): global_load_lds imm offset != 0 corrupts the transfer — the
// offset participates in the LDS-side address. ALWAYS pass offset=0 and bake
// the displacement into the pointer (gA + 32 below).
// NEW (R10): outputs stored as bf16 (halves write traffic + select's reads;
// error budget analysis: bf16 ulp=16 on d2~4096 -> mean shift ~0.01 vs
// threshold 0.0797).
//   Out[m][n] = bf16( a2[m] + c2[n] - 2 * sum_k A[m][k]*Cb[n][k] )
// ---------------------------------------------------------------------------
__global__ __launch_bounds__(256, 3) void gemm_d2_fused(const bf16_t* __restrict__ Fb,
                                                        const bf16_t* __restrict__ Cb,
                                                        const float* __restrict__ f2,
                                                        const float* __restrict__ c2,
                                                        bf16_t* __restrict__ Dfc,
                                                        bf16_t* __restrict__ Dcc) {
    __shared__ __align__(16) bf16_t As[2][128 * 32];
    __shared__ __align__(16) bf16_t Bs[2][128 * 32];

    const int tid  = threadIdx.x;
    const int wave = tid >> 6;
    const int lane = tid & 63;

    const int by = blockIdx.y;
    const bf16_t* A; const float* a2v; bf16_t* Out; int bm;
    if (by < B_ROWS / 128) { A = Fb; a2v = f2; Out = Dfc; bm = by * 128; }
    else { A = Cb; a2v = c2; Out = Dcc; bm = (by - B_ROWS / 128) * 128; }
    const int bn = blockIdx.x * 128;
    const int N = C_ROWS, K = D_DIM;

    const int wm = (wave >> 1) * 64;
    const int wn = (wave & 1) * 64;

    f32x4 acc[4][4] = {};

    const int c0   = wave * 2;
    const int rsub = lane >> 2;           // 0..15
    const int ksub = (lane & 3) * 8;      // 0,8,16,24 (16B)
    const int mrow = lane & 15;
    const int kq   = (lane >> 4) * 8;

    for (int k0 = 0; k0 < K; k0 += 64) {
        #pragma unroll
        for (int is = 0; is < 2; ++is) {
            int chunk = c0 + is;
            int row = chunk * 16 + rsub;
            const bf16_t* gA0 = A  + (size_t)(bm + row) * K + (k0 + ksub);
            const bf16_t* gB0 = Cb + (size_t)(bn + row) * K + (k0 + ksub);
            const bf16_t* gA1 = gA0 + 32;   // k0 + [32,64): explicit pointer,
            const bf16_t* gB1 = gB0 + 32;   // NEVER the builtin imm offset
            __builtin_amdgcn_global_load_lds(
                (const __attribute__((address_space(1))) void*)gA0,
                (__attribute__((address_space(3))) void*)&As[0][chunk * 512], 16, 0, 0);
            __builtin_amdgcn_global_load_lds(
                (const __attribute__((address_space(1))) void*)gB0,
                (__attribute__((address_space(3))) void*)&Bs[0][chunk * 512], 16, 0, 0);
            __builtin_amdgcn_global_load_lds(
                (const __attribute__((address_space(1))) void*)gA1,
                (__attribute__((address_space(3))) void*)&As[1][chunk * 512], 16, 0, 0);
            __builtin_amdgcn_global_load_lds(
                (const __attribute__((address_space(1))) void*)gB1,
                (__attribute__((address_space(3))) void*)&Bs[1][chunk * 512], 16, 0, 0);
        }
        __syncthreads();

        #pragma unroll
        for (int h = 0; h < 2; ++h) {
            bf16x8 af[4], bf_[4];
            #pragma unroll
            for (int i = 0; i < 4; ++i) {
                af[i]  = *(const bf16x8*)&As[h][(wm + i * 16 + mrow) * 32 + kq];
                bf_[i] = *(const bf16x8*)&Bs[h][(wn + i * 16 + mrow) * 32 + kq];
            }
            #pragma unroll
            for (int i = 0; i < 4; ++i)
                #pragma unroll
                for (int j = 0; j < 4; ++j)
                    acc[i][j] = __builtin_amdgcn_mfma_f32_16x16x32_bf16(af[i], bf_[j], acc[i][j], 0, 0, 0);
        }
        __syncthreads();
    }

    // Epilogue: d2 = a2[m] + c2[n] - 2*dot, stored bf16.
    // C/D: col=lane&15, row=(lane>>4)*4+reg
    const int ncol = lane & 15;
    const int r4   = (lane >> 4) * 4;
    #pragma unroll
    for (int i = 0; i < 4; ++i) {
        #pragma unroll
        for (int r = 0; r < 4; ++r) {
            int m = bm + wm + i * 16 + r4 + r;
            float am = a2v[m];
            #pragma unroll
            for (int j = 0; j < 4; ++j) {
                int n = bn + wn + j * 16 + ncol;
                Out[(size_t)m * N + n] = (bf16_t)(am + c2[n] - 2.0f * acc[i][j][r]);
            }
        }
    }
}

// ---------------------------------------------------------------------------
// select v3: bf16 distance rows, vectorized 16B loads.
// Per feature row b: iterative argmin w/ exclusion over Dfc row; trust test
// on demand from Dcc row sel:
//   label in near3[sel]  <=>  #{ j : (Dcc[sel][j], j) <lex (Dcc[sel][label],
//   label) } < NEAREST     (stable argsort -> lexicographic order)
// Element ownership: lane l, group g (0..3), sub e (0..7):
//   n = g*512 + l*8 + e ;  excl bit = g*8+e.
// 4 waves/block, one row per wave; one atomicAdd per block onto out.
// ---------------------------------------------------------------------------
__global__ __launch_bounds__(256) void select_kernel(const bf16_t* __restrict__ Dfc,
                                                     const bf16_t* __restrict__ Dcc,
                                                     float* __restrict__ out, int C) {
    int wave = threadIdx.x >> 6, lane = threadIdx.x & 63;
    int b = blockIdx.x * 4 + wave;
    int label = b / NUM;
    const bf16_t* row = Dfc + (size_t)b * C;

    float vals[32];
    #pragma unroll
    for (int g = 0; g < 4; ++g) {
        bf16x8 v = *(const bf16x8*)(row + g * 512 + lane * 8);
        #pragma unroll
        for (int e = 0; e < 8; ++e) {
            int n = g * 512 + lane * 8 + e;
            float f = (float)v[e];
            vals[g * 8 + e] = (n == label) ? INFINITY : f;
        }
    }

    unsigned int excl = 0;
    float min_diff = 0.0f;
    int found = 0;
    for (int it = 0; it < MAX_ITER; ++it) {
        float bestv = INFINITY; int bestidx = 0x7fffffff;
        #pragma unroll
        for (int g = 0; g < 4; ++g)
            #pragma unroll
            for (int e = 0; e < 8; ++e) {
                int bit = g * 8 + e;
                if (excl & (1u << bit)) continue;
                float v = vals[bit];
                int idx = g * 512 + lane * 8 + e;
                if (v < bestv || (v == bestv && idx < bestidx)) { bestv = v; bestidx = idx; }
            }
        for (int off = 32; off >= 1; off >>= 1) {
            float ov = __shfl_down(bestv, off); int oi = __shfl_down(bestidx, off);
            if (ov < bestv || (ov == bestv && oi < bestidx)) { bestv = ov; bestidx = oi; }
        }
        int sel = __shfl(bestidx, 0);
        float selv = __shfl(bestv, 0);

        // --- on-demand trust: count lex-smaller entries of Dcc row sel ---
        const bf16_t* crow = Dcc + (size_t)sel * C;
        float dl = (float)crow[label];          // uniform address: broadcast
        int cnt = 0;
        #pragma unroll
        for (int g = 0; g < 4; ++g) {
            bf16x8 v = *(const bf16x8*)(crow + g * 512 + lane * 8);
            #pragma unroll
            for (int e = 0; e < 8; ++e) {
                int idx = g * 512 + lane * 8 + e;
                float f = (float)v[e];
                cnt += (f < dl || (f == dl && idx < label)) ? 1 : 0;
            }
        }
        #pragma unroll
        for (int off = 32; off >= 1; off >>= 1) cnt += __shfl_down(cnt, off);
        cnt = __shfl(cnt, 0);
        bool trusted = (cnt >= NEAREST);

        if (trusted) { min_diff = sqrtf(fmaxf(selv, 0.0f)); found = 1; break; }
        if (((sel >> 3) & 63) == lane) excl |= 1u << (((sel >> 9) << 3) | (sel & 7));
    }
    __shared__ float hs[4];
    if (lane == 0) {
        float same = sqrtf(fmaxf((float)row[label], 0.0f));
        float md = found ? min_diff : 0.0f;
        hs[wave] = fmaxf(MARGIN + same - md, 0.0f);
    }
    __syncthreads();
    if (threadIdx.x == 0)
        atomicAdd(out, (hs[0] + hs[1] + hs[2] + hs[3]) * (1.0f / (float)B_ROWS));
}

// ---------------------------------------------------------------------------
extern "C" void kernel_launch(void* const* d_in, const int* in_sizes, int n_in,
                              void* d_out, int out_size, void* d_ws, size_t ws_size,
                              hipStream_t stream) {
    const float* feature = (const float*)d_in[0];  // 4096 x 2048
    const float* centers = (const float*)d_in[1];  // 2048 x 2048
    float* out = (float*)d_out;                    // scalar

    // Workspace layout (Dfc/Dcc now bf16)
    bf16_t* Dfc  = (bf16_t*)d_ws;                            // 4096*2048 bf16
    bf16_t* Dcc  = Dfc + (size_t)B_ROWS * C_ROWS;            // 2048*2048 bf16
    bf16_t* Fbf  = Dcc + (size_t)C_ROWS * C_ROWS;            // 4096*2048 bf16
    bf16_t* Cbf  = Fbf + (size_t)B_ROWS * D_DIM;             // 2048*2048 bf16
    float*  f2   = (float*)(Cbf + (size_t)C_ROWS * D_DIM);   // 4096
    float*  c2   = f2 + B_ROWS;                              // 2048

    conv_rows<<<(B_ROWS + C_ROWS) / 4, 256, 0, stream>>>(feature, centers, Fbf, Cbf,
                                                         f2, c2, out);

    // Both distance matrices in one dispatch: grid (16, 32+16) = 768 blocks.
    gemm_d2_fused<<<dim3(C_ROWS / 128, B_ROWS / 128 + C_ROWS / 128), 256, 0, stream>>>(
        Fbf, Cbf, f2, c2, Dfc, Dcc);

    // select with on-demand trust (reads Dcc directly; no near3 dispatch).
    select_kernel<<<B_ROWS / 4, 256, 0, stream>>>(Dfc, Dcc, out, C_ROWS);
}